// Round 15
// baseline (49.029 us; speedup 1.0000x reference)
//
#include <hip/hip_runtime.h>
#include <math.h>

#define T_LEN 2048
#define LN_EPS 1e-5f
#define M_ROWS 8192

using u16x8  = __attribute__((ext_vector_type(8))) unsigned short;
using bf16x8 = __attribute__((ext_vector_type(8))) short;
using f32x4  = __attribute__((ext_vector_type(4))) float;

__device__ __forceinline__ unsigned short f2bf(float f) {
    unsigned int u = __float_as_uint(f);
    u += 0x7FFFu + ((u >> 16) & 1u);
    return (unsigned short)(u >> 16);
}
__device__ __forceinline__ float bf2f(unsigned short u) {
    return __uint_as_float(((unsigned int)u) << 16);
}
__device__ __forceinline__ u16x8 pack8(float4 a, float4 c) {
    u16x8 p;
    p[0] = f2bf(a.x); p[1] = f2bf(a.y); p[2] = f2bf(a.z); p[3] = f2bf(a.w);
    p[4] = f2bf(c.x); p[5] = f2bf(c.y); p[6] = f2bf(c.z); p[7] = f2bf(c.w);
    return p;
}
// LDS-visibility barrier that does NOT drain vmcnt (keeps B prefetch in flight)
__device__ __forceinline__ void bar_lds() {
    asm volatile("s_waitcnt lgkmcnt(0)" ::: "memory");
    __builtin_amdgcn_s_barrier();
}

// ---------------------------------------------------------------------------
// K,V GEMM from fp32 inputs (identical to round 14).
// ---------------------------------------------------------------------------
__global__ __launch_bounds__(512) void kv_gemm_f32(
    const float* __restrict__ A, const float* __restrict__ Wqkv,
    const float* __restrict__ bias,
    const float* __restrict__ wo, const float* __restrict__ w1,
    const float* __restrict__ w2,
    unsigned short* __restrict__ KV, unsigned short* __restrict__ wconv)
{
    __shared__ char sm[2][32768];

    const int tid = threadIdx.x, lane = tid & 63, wid = tid >> 6;
    const int wr = wid >> 2, wcl = wid & 3;
    const int m0 = blockIdx.x * 128, n0 = blockIdx.y * 128;

    {   // side job: weight conversion (wq|wo|w1|w2 -> bf16)
        const int bid = blockIdx.y * 64 + blockIdx.x;
        const int g = bid * 512 + tid;
        if (g < 49152) {
            const int e = g * 8;
            const float* src; int off;
            if (e < 65536)       { src = Wqkv; off = 0; }
            else if (e < 131072) { src = wo;   off = 65536; }
            else if (e < 262144) { src = w1;   off = 131072; }
            else                 { src = w2;   off = 262144; }
            const float4 a = *(const float4*)(src + (e - off));
            const float4 c = *(const float4*)(src + (e - off) + 4);
            *(u16x8*)(wconv + e) = pack8(a, c);
        }
    }

    float4 ld[4][2];
    auto LOADR = [&](int k0) {
        #pragma unroll
        for (int j = 0; j < 4; ++j) {
            const int i = j * 512 + tid;
            const float* src;
            if (i < 1024) {
                const int row = i >> 3, k8 = i & 7;
                src = A + (size_t)(m0 + row) * 256 + k0 + k8 * 8;
            } else {
                const int ii = i - 1024;
                const int row = ii >> 3, k8 = ii & 7;
                src = Wqkv + (size_t)(256 + n0 + row) * 256 + k0 + k8 * 8;
            }
            ld[j][0] = *(const float4*)src;
            ld[j][1] = *(const float4*)(src + 4);
        }
    };
    auto CWRITE = [&](char* buf) {
        #pragma unroll
        for (int j = 0; j < 4; ++j) {
            const int i = j * 512 + tid;
            const u16x8 p = pack8(ld[j][0], ld[j][1]);
            if (i < 1024) {
                const int row = i >> 3, k8 = i & 7;
                *(u16x8*)(buf + ((row * 128 + k8 * 16) ^ ((row & 7) << 4))) = p;
            } else {
                const int ii = i - 1024;
                const int row = ii >> 3, k8 = ii & 7;
                *(u16x8*)(buf + 16384 + ((row * 128 + k8 * 16) ^ ((row & 7) << 4))) = p;
            }
        }
    };

    f32x4 acc[4][2];
    #pragma unroll
    for (int m = 0; m < 4; ++m)
        #pragma unroll
        for (int n = 0; n < 2; ++n) acc[m][n] = (f32x4)(0.f);

    LOADR(0);
    CWRITE(sm[0]);
    __syncthreads();

    #pragma unroll
    for (int k = 0; k < 4; ++k) {
        if (k < 3) LOADR((k + 1) * 64);
        char* As = sm[k & 1];
        char* Ws = sm[k & 1] + 16384;
        #pragma unroll
        for (int ks = 0; ks < 2; ++ks) {
            bf16x8 af[4], bfr[2];
            #pragma unroll
            for (int m = 0; m < 4; ++m) {
                const int row = wr * 64 + m * 16 + (lane & 15);
                const int off = (row * 128 + ks * 64 + (lane >> 4) * 16) ^ ((row & 7) << 4);
                af[m] = *(const bf16x8*)(As + off);
            }
            #pragma unroll
            for (int n = 0; n < 2; ++n) {
                const int row = wcl * 32 + n * 16 + (lane & 15);
                const int off = (row * 128 + ks * 64 + (lane >> 4) * 16) ^ ((row & 7) << 4);
                bfr[n] = *(const bf16x8*)(Ws + off);
            }
            #pragma unroll
            for (int m = 0; m < 4; ++m)
                #pragma unroll
                for (int n = 0; n < 2; ++n)
                    acc[m][n] = __builtin_amdgcn_mfma_f32_16x16x32_bf16(
                        af[m], bfr[n], acc[m][n], 0, 0, 0);
        }
        if (k < 3) CWRITE(sm[(k + 1) & 1]);
        __syncthreads();
    }

    #pragma unroll
    for (int n = 0; n < 2; ++n) {
        const int c = n0 + wcl * 32 + n * 16 + (lane & 15);
        const float bv = bias[256 + c];
        #pragma unroll
        for (int m = 0; m < 4; ++m) {
            const int rbase = m0 + wr * 64 + m * 16 + ((lane >> 4) << 2);
            #pragma unroll
            for (int j = 0; j < 4; ++j)
                KV[(size_t)(rbase + j) * 512 + c] = f2bf(acc[m][n][j] + bv);
        }
    }
}

// ---------------------------------------------------------------------------
// Fused tail, B-in-registers: feat->bf16 | Q GEMM | attention | out-proj+LN1
// | FFN1 | FFN2+LN2. Weights load global->VGPR (issued one phase early);
// A-operands in swizzled LDS; barrier-free phases (8 lgkm barriers total).
// LDS: smA 16K | smH 32K (aliases smF+smQ early) | part 2K = 50 KB.
// ---------------------------------------------------------------------------
__global__ __launch_bounds__(512) void tail_fused_regB(
    const unsigned short* __restrict__ kv, const unsigned short* __restrict__ wconv,
    const float* __restrict__ features, const float* __restrict__ b_qkv,
    const float* __restrict__ b_out,
    const float* __restrict__ g1, const float* __restrict__ be1,
    const float* __restrict__ b1, const float* __restrict__ b2,
    const float* __restrict__ g2, const float* __restrict__ be2,
    float* __restrict__ out)
{
    __shared__ __align__(16) char sm[51200];
    char* smA = sm;                      // [32][512 B]  = 16384
    char* smH = sm + 16384;              // [32][1024 B] = 32768
    char* smF = smH;                     // alias: [32][512 B] (feat bf16)
    char* smQ = smH + 16384;             // alias: [32][512 B] (Q bf16)
    float* part = (float*)(sm + 49152);  // [8][32][2]

    const int tid = threadIdx.x, lane = tid & 63, wid = tid >> 6;
    const int m0 = blockIdx.x * 32;
    const int b = m0 >> 11, t0 = m0 & 2047;
    const int rowB = wid * 32 + (lane & 15);   // this lane's B-row for n=0
    const int kofs = (lane >> 4) * 8;

    const unsigned short* Wq = wconv;
    const unsigned short* Wo = wconv + 65536;
    const unsigned short* W1 = wconv + 131072;
    const unsigned short* W2 = wconv + 262144;

    // ---- issue Q-weight fragments first (land during P-F) ----
    bf16x8 Bq[8][2];
    #pragma unroll
    for (int kc = 0; kc < 8; ++kc)
        #pragma unroll
        for (int n = 0; n < 2; ++n)
            Bq[kc][n] = *(const bf16x8*)(Wq + (size_t)(rowB + n * 16) * 256
                                         + kc * 32 + kofs);

    // ========== P-F: features rows t0..t0+31 -> smF bf16 (swizzled) ==========
    #pragma unroll
    for (int j = 0; j < 2; ++j) {
        const int i = j * 512 + tid;
        const int e = i >> 5, ch = i & 31;
        const float* src = features + ((size_t)(b * T_LEN + t0 + e)) * 256 + ch * 8;
        const float4 a = *(const float4*)src;
        const float4 c = *(const float4*)(src + 4);
        *(u16x8*)(smF + e * 512 + ((ch ^ (e & 7)) << 4)) = pack8(a, c);
    }
    bar_lds();

    bf16x8 Bo[8][2];   // out-proj weights (issued after Q compute)

    // ========== P-Q: Q GEMM 32x256 (barrier-free) ==========
    {
        f32x4 acc[2][2];
        #pragma unroll
        for (int m = 0; m < 2; ++m)
            #pragma unroll
            for (int n = 0; n < 2; ++n) acc[m][n] = (f32x4)(0.f);

        #pragma unroll
        for (int kc = 0; kc < 8; ++kc) {
            bf16x8 af[2];
            #pragma unroll
            for (int m = 0; m < 2; ++m) {
                const int r = m * 16 + (lane & 15);
                const int ch = kc * 4 + (lane >> 4);
                af[m] = *(const bf16x8*)(smF + r * 512 + ((ch ^ (r & 7)) << 4));
            }
            #pragma unroll
            for (int m = 0; m < 2; ++m)
                #pragma unroll
                for (int n = 0; n < 2; ++n)
                    acc[m][n] = __builtin_amdgcn_mfma_f32_16x16x32_bf16(
                        af[m], Bq[kc][n], acc[m][n], 0, 0, 0);
        }

        // issue Wo fragments (land during Q-epilogue + attention)
        #pragma unroll
        for (int kc = 0; kc < 8; ++kc)
            #pragma unroll
            for (int n = 0; n < 2; ++n)
                Bo[kc][n] = *(const bf16x8*)(Wo + (size_t)(rowB + n * 16) * 256
                                             + kc * 32 + kofs);

        // Q epilogue: + b_qkv[0..255] -> smQ (bf16, swizzled)
        #pragma unroll
        for (int n = 0; n < 2; ++n) {
            const int c = wid * 32 + n * 16 + (lane & 15);
            const float bv = b_qkv[c];
            #pragma unroll
            for (int m = 0; m < 2; ++m) {
                const int rb = m * 16 + ((lane >> 4) << 2);
                #pragma unroll
                for (int j = 0; j < 4; ++j) {
                    const int r = rb + j;
                    const int addr = r * 512 + (((c >> 3) ^ (r & 7)) << 4) + ((c & 7) << 1);
                    *(unsigned short*)(smQ + addr) = f2bf(acc[m][n][j] + bv);
                }
            }
        }
    }
    bar_lds();

    // ========== attention: Q from LDS, K/V from kv global ==========
    {
        const int half = tid & 1, p = tid >> 1;
        const int h = p & 7, tl = p >> 3;
        const int t = t0 + tl;
        const unsigned short* kvb = kv + (size_t)b * T_LEN * 512;

        float q[16];
        #pragma unroll
        for (int jj = 0; jj < 2; ++jj) {
            const int ch = h * 4 + half * 2 + jj;
            u16x8 u = *(const u16x8*)(smQ + tl * 512 + ((ch ^ (tl & 7)) << 4));
            #pragma unroll
            for (int e = 0; e < 8; ++e) q[jj * 8 + e] = bf2f(u[e]);
        }
        const unsigned short* kbase = kvb + h * 32 + half * 16;
        const unsigned short* vbase = kvb + 256 + h * 32 + half * 16;

        float sc[9], mx = -1e30f;
        #pragma unroll
        for (int j = 0; j < 9; ++j) {
            const int kr0 = t - 4 + j;
            const int krm = min(max(kr0, 0), T_LEN - 1);
            const unsigned short* kr = kbase + (size_t)krm * 512;
            float d = 0.f;
            #pragma unroll
            for (int jj = 0; jj < 2; ++jj) {
                u16x8 u = *(const u16x8*)(kr + jj * 8);
                #pragma unroll
                for (int e = 0; e < 8; ++e) d += q[jj * 8 + e] * bf2f(u[e]);
            }
            d += __shfl_xor(d, 1);
            sc[j] = (kr0 == krm) ? d * 0.17677669529663687f : -1e30f;
            mx = fmaxf(mx, sc[j]);
        }
        float sum = 0.f;
        #pragma unroll
        for (int j = 0; j < 9; ++j) { sc[j] = expf(sc[j] - mx); sum += sc[j]; }
        const float inv = 1.f / sum;

        float ov[16] = {};
        #pragma unroll
        for (int j = 0; j < 9; ++j) {
            const float pj = sc[j] * inv;
            const int krm = min(max(t - 4 + j, 0), T_LEN - 1);
            const unsigned short* vr = vbase + (size_t)krm * 512;
            #pragma unroll
            for (int jj = 0; jj < 2; ++jj) {
                u16x8 u = *(const u16x8*)(vr + jj * 8);
                #pragma unroll
                for (int e = 0; e < 8; ++e) ov[jj * 8 + e] += pj * bf2f(u[e]);
            }
        }
        #pragma unroll
        for (int jj = 0; jj < 2; ++jj) {
            u16x8 p8;
            #pragma unroll
            for (int e = 0; e < 8; ++e) p8[e] = f2bf(ov[jj * 8 + e]);
            const int ch = h * 4 + half * 2 + jj;
            *(u16x8*)(smA + tl * 512 + ((ch ^ (tl & 7)) << 4)) = p8;
        }
    }
    bar_lds();

    float xres[2][2][4];
    bf16x8 B1a[8][2];   // FFN1 half-0 weights

    // ========== P-B: out-proj 32x256 + res + LN1 ==========
    {
        f32x4 acc[2][2];
        #pragma unroll
        for (int m = 0; m < 2; ++m)
            #pragma unroll
            for (int n = 0; n < 2; ++n) acc[m][n] = (f32x4)(0.f);

        #pragma unroll
        for (int kc = 0; kc < 8; ++kc) {
            bf16x8 af[2];
            #pragma unroll
            for (int m = 0; m < 2; ++m) {
                const int r = m * 16 + (lane & 15);
                const int ch = kc * 4 + (lane >> 4);
                af[m] = *(const bf16x8*)(smA + r * 512 + ((ch ^ (r & 7)) << 4));
            }
            #pragma unroll
            for (int m = 0; m < 2; ++m)
                #pragma unroll
                for (int n = 0; n < 2; ++n)
                    acc[m][n] = __builtin_amdgcn_mfma_f32_16x16x32_bf16(
                        af[m], Bo[kc][n], acc[m][n], 0, 0, 0);
        }

        // issue FFN1 half-0 weights (land during LN1 epilogue)
        #pragma unroll
        for (int kc = 0; kc < 8; ++kc)
            #pragma unroll
            for (int n = 0; n < 2; ++n)
                B1a[kc][n] = *(const bf16x8*)(W1 + (size_t)(rowB + n * 16) * 256
                                              + kc * 32 + kofs);

        // LN1 epilogue: + b_out + features(res), LN -> smA + xres
        float v[2][2][4], s[2][4], sq[2][4];
        #pragma unroll
        for (int m = 0; m < 2; ++m)
            #pragma unroll
            for (int j = 0; j < 4; ++j) { s[m][j] = 0.f; sq[m][j] = 0.f; }
        #pragma unroll
        for (int n = 0; n < 2; ++n) {
            const int c = wid * 32 + n * 16 + (lane & 15);
            const float bv = b_out[c];
            #pragma unroll
            for (int m = 0; m < 2; ++m) {
                const int rb = m * 16 + ((lane >> 4) << 2);
                #pragma unroll
                for (int j = 0; j < 4; ++j) {
                    float x = acc[m][n][j] + bv
                            + features[(size_t)(m0 + rb + j) * 256 + c];
                    v[m][n][j] = x; s[m][j] += x; sq[m][j] += x * x;
                }
            }
        }
        #pragma unroll
        for (int m = 0; m < 2; ++m)
            #pragma unroll
            for (int j = 0; j < 4; ++j) {
                #pragma unroll
                for (int msk = 1; msk <= 8; msk <<= 1) {
                    s[m][j]  += __shfl_xor(s[m][j], msk);
                    sq[m][j] += __shfl_xor(sq[m][j], msk);
                }
                if ((lane & 15) == 0) {
                    const int r = m * 16 + ((lane >> 4) << 2) + j;
                    part[(wid * 32 + r) * 2 + 0] = s[m][j];
                    part[(wid * 32 + r) * 2 + 1] = sq[m][j];
                }
            }
        bar_lds();
        #pragma unroll
        for (int m = 0; m < 2; ++m) {
            const int rb = m * 16 + ((lane >> 4) << 2);
            #pragma unroll
            for (int j = 0; j < 4; ++j) {
                const int r = rb + j;
                float S = 0.f, SQ = 0.f;
                #pragma unroll
                for (int w = 0; w < 8; ++w) {
                    S += part[(w * 32 + r) * 2 + 0]; SQ += part[(w * 32 + r) * 2 + 1];
                }
                const float mean = S * (1.f / 256.f);
                const float var  = SQ * (1.f / 256.f) - mean * mean;
                const float rstd = rsqrtf(var + LN_EPS);
                #pragma unroll
                for (int n = 0; n < 2; ++n) {
                    const int c = wid * 32 + n * 16 + (lane & 15);
                    const float o = (v[m][n][j] - mean) * rstd * g1[c] + be1[c];
                    xres[m][n][j] = o;
                    const int addr = r * 512 + (((c >> 3) ^ (r & 7)) << 4) + ((c & 7) << 1);
                    *(unsigned short*)(smA + addr) = f2bf(o);
                }
            }
        }
    }
    bar_lds();

    // ========== P-C: FFN1 (two 256-col halves), writes smH ==========
    {
        bf16x8 B1b[8][2];
        #pragma unroll
        for (int kc = 0; kc < 8; ++kc)     // half-1 weights (land during half-0)
            #pragma unroll
            for (int n = 0; n < 2; ++n)
                B1b[kc][n] = *(const bf16x8*)(W1 + (size_t)(256 + rowB + n * 16) * 256
                                              + kc * 32 + kofs);

        bf16x8 B2a[8][2];                  // FFN2 kc 0..7 (issued mid-phase)

        #pragma unroll
        for (int nh = 0; nh < 2; ++nh) {
            f32x4 acc[2][2];
            #pragma unroll
            for (int m = 0; m < 2; ++m)
                #pragma unroll
                for (int n = 0; n < 2; ++n) acc[m][n] = (f32x4)(0.f);

            #pragma unroll
            for (int kc = 0; kc < 8; ++kc) {
                bf16x8 af[2];
                #pragma unroll
                for (int m = 0; m < 2; ++m) {
                    const int r = m * 16 + (lane & 15);
                    const int ch = kc * 4 + (lane >> 4);
                    af[m] = *(const bf16x8*)(smA + r * 512 + ((ch ^ (r & 7)) << 4));
                }
                #pragma unroll
                for (int m = 0; m < 2; ++m)
                    #pragma unroll
                    for (int n = 0; n < 2; ++n)
                        acc[m][n] = __builtin_amdgcn_mfma_f32_16x16x32_bf16(
                            af[m], nh == 0 ? B1a[kc][n] : B1b[kc][n],
                            acc[m][n], 0, 0, 0);
            }
            if (nh == 0) {
                // issue FFN2 first-half weights
                #pragma unroll
                for (int kc = 0; kc < 8; ++kc)
                    #pragma unroll
                    for (int n = 0; n < 2; ++n)
                        B2a[kc][n] = *(const bf16x8*)(W2 + (size_t)(rowB + n * 16) * 512
                                                      + kc * 32 + kofs);
            }
            // epilogue: relu(acc + b1) -> smH (swizzled)
            #pragma unroll
            for (int n = 0; n < 2; ++n) {
                const int c = nh * 256 + wid * 32 + n * 16 + (lane & 15);
                const float bv = b1[c];
                #pragma unroll
                for (int m = 0; m < 2; ++m) {
                    const int rb = m * 16 + ((lane >> 4) << 2);
                    #pragma unroll
                    for (int j = 0; j < 4; ++j) {
                        const int rr = rb + j;
                        const int addr = rr * 1024 + (((c >> 3) ^ (rr & 7)) << 4)
                                       + ((c & 7) << 1);
                        *(unsigned short*)(smH + addr) =
                            f2bf(fmaxf(acc[m][n][j] + bv, 0.f));
                    }
                }
            }
        }

        bar_lds();   // smH complete

        // ========== P-D: FFN2 K=512 + xres + LN2 -> out ==========
        f32x4 acc[2][2];
        #pragma unroll
        for (int m = 0; m < 2; ++m)
            #pragma unroll
            for (int n = 0; n < 2; ++n) acc[m][n] = (f32x4)(0.f);

        bf16x8 B2b[8][2];
        #pragma unroll
        for (int kc = 0; kc < 8; ++kc)     // second-half weights (kc 8..15)
            #pragma unroll
            for (int n = 0; n < 2; ++n)
                B2b[kc][n] = *(const bf16x8*)(W2 + (size_t)(rowB + n * 16) * 512
                                              + 256 + kc * 32 + kofs);

        #pragma unroll
        for (int kc = 0; kc < 8; ++kc) {
            bf16x8 af[2];
            #pragma unroll
            for (int m = 0; m < 2; ++m) {
                const int r = m * 16 + (lane & 15);
                const int ch = kc * 4 + (lane >> 4);
                af[m] = *(const bf16x8*)(smH + r * 1024 + ((ch ^ (r & 7)) << 4));
            }
            #pragma unroll
            for (int m = 0; m < 2; ++m)
                #pragma unroll
                for (int n = 0; n < 2; ++n)
                    acc[m][n] = __builtin_amdgcn_mfma_f32_16x16x32_bf16(
                        af[m], B2a[kc][n], acc[m][n], 0, 0, 0);
        }
        #pragma unroll
        for (int kc = 0; kc < 8; ++kc) {
            bf16x8 af[2];
            #pragma unroll
            for (int m = 0; m < 2; ++m) {
                const int r = m * 16 + (lane & 15);
                const int ch = (kc + 8) * 4 + (lane >> 4);
                af[m] = *(const bf16x8*)(smH + r * 1024 + ((ch ^ (r & 7)) << 4));
            }
            #pragma unroll
            for (int m = 0; m < 2; ++m)
                #pragma unroll
                for (int n = 0; n < 2; ++n)
                    acc[m][n] = __builtin_amdgcn_mfma_f32_16x16x32_bf16(
                        af[m], B2b[kc][n], acc[m][n], 0, 0, 0);
        }

        // LN2 epilogue -> out
        float v[2][2][4], s[2][4], sq[2][4];
        #pragma unroll
        for (int m = 0; m < 2; ++m)
            #pragma unroll
            for (int j = 0; j < 4; ++j) { s[m][j] = 0.f; sq[m][j] = 0.f; }
        #pragma unroll
        for (int n = 0; n < 2; ++n) {
            const int c = wid * 32 + n * 16 + (lane & 15);
            const float bv = b2[c];
            #pragma unroll
            for (int m = 0; m < 2; ++m) {
                #pragma unroll
                for (int j = 0; j < 4; ++j) {
                    float x = acc[m][n][j] + bv + xres[m][n][j];
                    v[m][n][j] = x; s[m][j] += x; sq[m][j] += x * x;
                }
            }
        }
        #pragma unroll
        for (int m = 0; m < 2; ++m)
            #pragma unroll
            for (int j = 0; j < 4; ++j) {
                #pragma unroll
                for (int msk = 1; msk <= 8; msk <<= 1) {
                    s[m][j]  += __shfl_xor(s[m][j], msk);
                    sq[m][j] += __shfl_xor(sq[m][j], msk);
                }
                if ((lane & 15) == 0) {
                    const int r = m * 16 + ((lane >> 4) << 2) + j;
                    part[(wid * 32 + r) * 2 + 0] = s[m][j];
                    part[(wid * 32 + r) * 2 + 1] = sq[m][j];
                }
            }
        bar_lds();
        #pragma unroll
        for (int m = 0; m < 2; ++m) {
            const int rb = m * 16 + ((lane >> 4) << 2);
            #pragma unroll
            for (int j = 0; j < 4; ++j) {
                const int r = rb + j;
                float S = 0.f, SQ = 0.f;
                #pragma unroll
                for (int w = 0; w < 8; ++w) {
                    S += part[(w * 32 + r) * 2 + 0]; SQ += part[(w * 32 + r) * 2 + 1];
                }
                const float mean = S * (1.f / 256.f);
                const float var  = SQ * (1.f / 256.f) - mean * mean;
                const float rstd = rsqrtf(var + LN_EPS);
                #pragma unroll
                for (int n = 0; n < 2; ++n) {
                    const int c = wid * 32 + n * 16 + (lane & 15);
                    out[(size_t)(m0 + r) * 256 + c] =
                        (v[m][n][j] - mean) * rstd * g2[c] + be2[c];
                }
            }
        }
    }
}

// ---------------------------------------------------------------------------
extern "C" void kernel_launch(void* const* d_in, const int* in_sizes, int n_in,
                              void* d_out, int out_size, void* d_ws, size_t ws_size,
                              hipStream_t stream) {
    const float* features = (const float*)d_in[0];
    const float* w_qkv    = (const float*)d_in[1];
    const float* b_qkv    = (const float*)d_in[2];
    const float* w_out    = (const float*)d_in[3];
    const float* b_out    = (const float*)d_in[4];
    const float* w1       = (const float*)d_in[5];
    const float* b1       = (const float*)d_in[6];
    const float* w2       = (const float*)d_in[7];
    const float* b2       = (const float*)d_in[8];
    const float* g1       = (const float*)d_in[9];
    const float* be1      = (const float*)d_in[10];
    const float* g2       = (const float*)d_in[11];
    const float* be2      = (const float*)d_in[12];
    // d_in[13] (mask) structurally determined by WIN=9 -> not read.

    unsigned short* wsu = (unsigned short*)d_ws;
    unsigned short* wconv = wsu;                // wq|wo|w1|w2 bf16: 393,216 els
    unsigned short* kvbf  = wsu + 393216;       // [8192][512]

    // 1) K,V projection (fp32-direct) + weight conversion (incl. Wq)
    kv_gemm_f32<<<dim3(64, 4), 512, 0, stream>>>(
        features, w_qkv, b_qkv, w_out, w1, w2, kvbf, wconv);
    // 2) fused tail: Q -> attention -> out-proj+LN1 -> FFN1 -> FFN2+LN2
    tail_fused_regB<<<M_ROWS / 32, 512, 0, stream>>>(
        kvbf, wconv, features, b_qkv, b_out, g1, be1, b1, b2, g2, be2,
        (float*)d_out);
}

// Round 16
// 38.323 us; speedup vs baseline: 1.2794x; 1.2794x over previous
//
#include <hip/hip_runtime.h>
#include <math.h>

#define T_LEN 2048
#define LN_EPS 1e-5f
#define M_ROWS 8192

using u16x8  = __attribute__((ext_vector_type(8))) unsigned short;
using bf16x8 = __attribute__((ext_vector_type(8))) short;
using f32x4  = __attribute__((ext_vector_type(4))) float;

__device__ __forceinline__ unsigned short f2bf(float f) {
    unsigned int u = __float_as_uint(f);
    u += 0x7FFFu + ((u >> 16) & 1u);
    return (unsigned short)(u >> 16);
}
__device__ __forceinline__ float bf2f(unsigned short u) {
    return __uint_as_float(((unsigned int)u) << 16);
}
__device__ __forceinline__ u16x8 pack8(float4 a, float4 c) {
    u16x8 p;
    p[0] = f2bf(a.x); p[1] = f2bf(a.y); p[2] = f2bf(a.z); p[3] = f2bf(a.w);
    p[4] = f2bf(c.x); p[5] = f2bf(c.y); p[6] = f2bf(c.z); p[7] = f2bf(c.w);
    return p;
}
__device__ __forceinline__ void gload16(const void* g, void* l) {
    __builtin_amdgcn_global_load_lds(
        (const __attribute__((address_space(1))) unsigned int*)g,
        (__attribute__((address_space(3))) unsigned int*)l, 16, 0, 0);
}
// counted round-barrier: newest 4 loads may stay in flight
__device__ __forceinline__ void bar_vm4() {
    asm volatile("s_waitcnt vmcnt(4)" ::: "memory");
    __builtin_amdgcn_s_barrier();
}
// draining round-barrier (pipeline tail)
__device__ __forceinline__ void bar_vm0() {
    asm volatile("s_waitcnt vmcnt(0)" ::: "memory");
    __builtin_amdgcn_s_barrier();
}

// ---------------------------------------------------------------------------
// K,V GEMM from fp32 inputs: kv[8192,512] = feat @ Wqkv[rows 256..767]^T + b.
// 64x128 tile, 512 threads (8 waves, 2x4), grid 128x4 = 512 (2 blocks/CU).
// Reg-staged convert, dbuf. Side job: convert wq|wo|w1|w2 -> bf16 wconv.
// ---------------------------------------------------------------------------
__global__ __launch_bounds__(512) void kv_gemm_f32(
    const float* __restrict__ A, const float* __restrict__ Wqkv,
    const float* __restrict__ bias,
    const float* __restrict__ wo, const float* __restrict__ w1,
    const float* __restrict__ w2,
    unsigned short* __restrict__ KV, unsigned short* __restrict__ wconv)
{
    __shared__ char sm[2][24576];        // per buf: As [64][64] 8K | Ws [128][64] 16K

    const int tid = threadIdx.x, lane = tid & 63, wid = tid >> 6;
    const int wr = wid >> 2, wcl = wid & 3;
    const int m0 = blockIdx.x * 64, n0 = blockIdx.y * 128;

    {   // side job: weight conversion (wq|wo|w1|w2 -> bf16)
        const int bid = blockIdx.y * 128 + blockIdx.x;
        const int g = bid * 512 + tid;
        if (g < 49152) {
            const int e = g * 8;
            const float* src; int off;
            if (e < 65536)       { src = Wqkv; off = 0; }
            else if (e < 131072) { src = wo;   off = 65536; }
            else if (e < 262144) { src = w1;   off = 131072; }
            else                 { src = w2;   off = 262144; }
            const float4 a = *(const float4*)(src + (e - off));
            const float4 c = *(const float4*)(src + (e - off) + 4);
            *(u16x8*)(wconv + e) = pack8(a, c);
        }
    }

    float4 ld[3][2];
    auto LOADR = [&](int k0) {
        #pragma unroll
        for (int j = 0; j < 3; ++j) {
            const int i = j * 512 + tid;          // 0..1535
            const float* src;
            if (i < 512) {
                const int row = i >> 3, k8 = i & 7;
                src = A + (size_t)(m0 + row) * 256 + k0 + k8 * 8;
            } else {
                const int ii = i - 512;
                const int row = ii >> 3, k8 = ii & 7;
                src = Wqkv + (size_t)(256 + n0 + row) * 256 + k0 + k8 * 8;
            }
            ld[j][0] = *(const float4*)src;
            ld[j][1] = *(const float4*)(src + 4);
        }
    };
    auto CWRITE = [&](char* buf) {
        #pragma unroll
        for (int j = 0; j < 3; ++j) {
            const int i = j * 512 + tid;
            const u16x8 p = pack8(ld[j][0], ld[j][1]);
            if (i < 512) {
                const int row = i >> 3, k8 = i & 7;
                *(u16x8*)(buf + ((row * 128 + k8 * 16) ^ ((row & 7) << 4))) = p;
            } else {
                const int ii = i - 512;
                const int row = ii >> 3, k8 = ii & 7;
                *(u16x8*)(buf + 8192 + ((row * 128 + k8 * 16) ^ ((row & 7) << 4))) = p;
            }
        }
    };

    f32x4 acc[2][2];
    #pragma unroll
    for (int m = 0; m < 2; ++m)
        #pragma unroll
        for (int n = 0; n < 2; ++n) acc[m][n] = (f32x4)(0.f);

    LOADR(0);
    CWRITE(sm[0]);
    __syncthreads();

    #pragma unroll
    for (int k = 0; k < 4; ++k) {
        if (k < 3) LOADR((k + 1) * 64);
        char* As = sm[k & 1];
        char* Ws = sm[k & 1] + 8192;
        #pragma unroll
        for (int ks = 0; ks < 2; ++ks) {
            bf16x8 af[2], bfr[2];
            #pragma unroll
            for (int m = 0; m < 2; ++m) {
                const int row = wr * 32 + m * 16 + (lane & 15);
                const int off = (row * 128 + ks * 64 + (lane >> 4) * 16) ^ ((row & 7) << 4);
                af[m] = *(const bf16x8*)(As + off);
            }
            #pragma unroll
            for (int n = 0; n < 2; ++n) {
                const int row = wcl * 32 + n * 16 + (lane & 15);
                const int off = (row * 128 + ks * 64 + (lane >> 4) * 16) ^ ((row & 7) << 4);
                bfr[n] = *(const bf16x8*)(Ws + off);
            }
            #pragma unroll
            for (int m = 0; m < 2; ++m)
                #pragma unroll
                for (int n = 0; n < 2; ++n)
                    acc[m][n] = __builtin_amdgcn_mfma_f32_16x16x32_bf16(
                        af[m], bfr[n], acc[m][n], 0, 0, 0);
        }
        if (k < 3) CWRITE(sm[(k + 1) & 1]);
        __syncthreads();
    }

    #pragma unroll
    for (int n = 0; n < 2; ++n) {
        const int c = n0 + wcl * 32 + n * 16 + (lane & 15);
        const float bv = bias[256 + c];
        #pragma unroll
        for (int m = 0; m < 2; ++m) {
            const int rbase = m0 + wr * 32 + m * 16 + ((lane >> 4) << 2);
            #pragma unroll
            for (int j = 0; j < 4; ++j)
                KV[(size_t)(rbase + j) * 512 + c] = f2bf(acc[m][n][j] + bv);
        }
    }
}

// ---------------------------------------------------------------------------
// Fused tail, 24-round counted-vmcnt pipeline (identical to round 14).
// ---------------------------------------------------------------------------
__global__ __launch_bounds__(512) void tail_fused_pipe2(
    const unsigned short* __restrict__ kv, const unsigned short* __restrict__ wconv,
    const float* __restrict__ features, const float* __restrict__ b_qkv,
    const float* __restrict__ b_out,
    const float* __restrict__ g1, const float* __restrict__ be1,
    const float* __restrict__ b1, const float* __restrict__ b2,
    const float* __restrict__ g2, const float* __restrict__ be2,
    float* __restrict__ out)
{
    __shared__ __align__(16) char sm[149504];
    char* smA = sm;                      // [32][512 B]  = 16384
    char* smH = sm + 114688;             // [32][1024 B] = 32768
    char* smF = smH;                     // alias: [32][512 B]
    char* smQ = smH + 16384;             // alias: [32][512 B]
    float* part = (float*)(sm + 147456); // [8][32][2]

    const int tid = threadIdx.x, lane = tid & 63, wid = tid >> 6;
    const int m0 = blockIdx.x * 32;
    const int b = m0 >> 11, t0 = m0 & 2047;

    const unsigned short* Wq = wconv;
    const unsigned short* Wo = wconv + 65536;
    const unsigned short* W1 = wconv + 131072;
    const unsigned short* W2 = wconv + 262144;

    auto stbuf = [&](int i) -> char* { return sm + 16384 + (i % 3) * 32768; };
    auto NSTAGE = [&](int i) {
        if (i >= 24) return;
        const unsigned short* W; int ldk, ro, k0;
        if (i < 4)       { W = Wq; ldk = 256; ro = 0;                    k0 = i * 64; }
        else if (i < 8)  { W = Wo; ldk = 256; ro = 0;                    k0 = (i - 4) * 64; }
        else if (i < 16) { W = W1; ldk = 256; ro = ((i - 8) >> 2) * 256; k0 = ((i - 8) & 3) * 64; }
        else             { W = W2; ldk = 512; ro = 0;                    k0 = (i - 16) * 64; }
        char* dst = stbuf(i);
        #pragma unroll
        for (int j = 0; j < 4; ++j) {
            const int ii = j * 512 + tid, row = ii >> 3, k8 = (ii & 7) ^ (row & 7);
            gload16(W + (size_t)(ro + row) * ldk + k0 + k8 * 8, dst + ii * 16);
        }
    };

    NSTAGE(0); NSTAGE(1);

    // ========== P-F: features rows t0..t0+31 -> smF bf16 (swizzled) ==========
    #pragma unroll
    for (int j = 0; j < 2; ++j) {
        const int i = j * 512 + tid;
        const int e = i >> 5, ch = i & 31;
        const float* src = features + ((size_t)(b * T_LEN + t0 + e)) * 256 + ch * 8;
        const float4 a = *(const float4*)src;
        const float4 c = *(const float4*)(src + 4);
        *(u16x8*)(smF + e * 512 + ((ch ^ (e & 7)) << 4)) = pack8(a, c);
    }
    __syncthreads();

    // ========== P-Q: Q GEMM 32x256, rounds 0..3 ==========
    {
        f32x4 acc[2][2];
        #pragma unroll
        for (int m = 0; m < 2; ++m)
            #pragma unroll
            for (int n = 0; n < 2; ++n) acc[m][n] = (f32x4)(0.f);

        #pragma unroll
        for (int i = 0; i < 4; ++i) {
            NSTAGE(i + 2);
            char* Bs = stbuf(i);
            #pragma unroll
            for (int ks = 0; ks < 2; ++ks) {
                bf16x8 af[2], bfr[2];
                #pragma unroll
                for (int m = 0; m < 2; ++m) {
                    const int r = m * 16 + (lane & 15);
                    const int ch = i * 8 + ks * 4 + (lane >> 4);
                    af[m] = *(const bf16x8*)(smF + r * 512 + ((ch ^ (r & 7)) << 4));
                }
                #pragma unroll
                for (int n = 0; n < 2; ++n) {
                    const int rB = wid * 32 + n * 16 + (lane & 15);
                    bfr[n] = *(const bf16x8*)(Bs + rB * 128
                             + (((ks * 4 + (lane >> 4)) ^ (rB & 7)) << 4));
                }
                #pragma unroll
                for (int m = 0; m < 2; ++m)
                    #pragma unroll
                    for (int n = 0; n < 2; ++n)
                        acc[m][n] = __builtin_amdgcn_mfma_f32_16x16x32_bf16(
                            af[m], bfr[n], acc[m][n], 0, 0, 0);
            }
            bar_vm4();
        }
        // Q epilogue: + b_qkv[0..255] -> smQ (bf16, swizzled)
        #pragma unroll
        for (int n = 0; n < 2; ++n) {
            const int c = wid * 32 + n * 16 + (lane & 15);
            const float bv = b_qkv[c];
            #pragma unroll
            for (int m = 0; m < 2; ++m) {
                const int rb = m * 16 + ((lane >> 4) << 2);
                #pragma unroll
                for (int j = 0; j < 4; ++j) {
                    const int r = rb + j;
                    const int addr = r * 512 + (((c >> 3) ^ (r & 7)) << 4) + ((c & 7) << 1);
                    *(unsigned short*)(smQ + addr) = f2bf(acc[m][n][j] + bv);
                }
            }
        }
    }
    __syncthreads();

    // ========== attention: Q from LDS, K/V from kv global ==========
    {
        const int half = tid & 1, p = tid >> 1;
        const int h = p & 7, tl = p >> 3;
        const int t = t0 + tl;
        const unsigned short* kvb = kv + (size_t)b * T_LEN * 512;

        float q[16];
        #pragma unroll
        for (int jj = 0; jj < 2; ++jj) {
            const int ch = h * 4 + half * 2 + jj;
            u16x8 u = *(const u16x8*)(smQ + tl * 512 + ((ch ^ (tl & 7)) << 4));
            #pragma unroll
            for (int e = 0; e < 8; ++e) q[jj * 8 + e] = bf2f(u[e]);
        }
        const unsigned short* kbase = kvb + h * 32 + half * 16;
        const unsigned short* vbase = kvb + 256 + h * 32 + half * 16;

        float sc[9], mx = -1e30f;
        #pragma unroll
        for (int j = 0; j < 9; ++j) {
            const int kr0 = t - 4 + j;
            const int krm = min(max(kr0, 0), T_LEN - 1);
            const unsigned short* kr = kbase + (size_t)krm * 512;
            float d = 0.f;
            #pragma unroll
            for (int jj = 0; jj < 2; ++jj) {
                u16x8 u = *(const u16x8*)(kr + jj * 8);
                #pragma unroll
                for (int e = 0; e < 8; ++e) d += q[jj * 8 + e] * bf2f(u[e]);
            }
            d += __shfl_xor(d, 1);
            sc[j] = (kr0 == krm) ? d * 0.17677669529663687f : -1e30f;
            mx = fmaxf(mx, sc[j]);
        }
        float sum = 0.f;
        #pragma unroll
        for (int j = 0; j < 9; ++j) { sc[j] = expf(sc[j] - mx); sum += sc[j]; }
        const float inv = 1.f / sum;

        float ov[16] = {};
        #pragma unroll
        for (int j = 0; j < 9; ++j) {
            const float pj = sc[j] * inv;
            const int krm = min(max(t - 4 + j, 0), T_LEN - 1);
            const unsigned short* vr = vbase + (size_t)krm * 512;
            #pragma unroll
            for (int jj = 0; jj < 2; ++jj) {
                u16x8 u = *(const u16x8*)(vr + jj * 8);
                #pragma unroll
                for (int e = 0; e < 8; ++e) ov[jj * 8 + e] += pj * bf2f(u[e]);
            }
        }
        #pragma unroll
        for (int jj = 0; jj < 2; ++jj) {
            u16x8 p8;
            #pragma unroll
            for (int e = 0; e < 8; ++e) p8[e] = f2bf(ov[jj * 8 + e]);
            const int ch = h * 4 + half * 2 + jj;
            *(u16x8*)(smA + tl * 512 + ((ch ^ (tl & 7)) << 4)) = p8;
        }
    }
    __syncthreads();

    float xres[2][2][4];

    // ========== P-B: out-proj, rounds 4..7 ==========
    {
        f32x4 acc[2][2];
        #pragma unroll
        for (int m = 0; m < 2; ++m)
            #pragma unroll
            for (int n = 0; n < 2; ++n) acc[m][n] = (f32x4)(0.f);

        #pragma unroll
        for (int i = 4; i < 8; ++i) {
            NSTAGE(i + 2);
            const int kk = i - 4;
            char* Bs = stbuf(i);
            #pragma unroll
            for (int ks = 0; ks < 2; ++ks) {
                bf16x8 af[2], bfr[2];
                #pragma unroll
                for (int m = 0; m < 2; ++m) {
                    const int r = m * 16 + (lane & 15);
                    const int ch = kk * 8 + ks * 4 + (lane >> 4);
                    af[m] = *(const bf16x8*)(smA + r * 512 + ((ch ^ (r & 7)) << 4));
                }
                #pragma unroll
                for (int n = 0; n < 2; ++n) {
                    const int rB = wid * 32 + n * 16 + (lane & 15);
                    bfr[n] = *(const bf16x8*)(Bs + rB * 128
                             + (((ks * 4 + (lane >> 4)) ^ (rB & 7)) << 4));
                }
                #pragma unroll
                for (int m = 0; m < 2; ++m)
                    #pragma unroll
                    for (int n = 0; n < 2; ++n)
                        acc[m][n] = __builtin_amdgcn_mfma_f32_16x16x32_bf16(
                            af[m], bfr[n], acc[m][n], 0, 0, 0);
            }
            bar_vm4();
        }

        // LN1 epilogue
        float v[2][2][4], s[2][4], sq[2][4];
        #pragma unroll
        for (int m = 0; m < 2; ++m)
            #pragma unroll
            for (int j = 0; j < 4; ++j) { s[m][j] = 0.f; sq[m][j] = 0.f; }
        #pragma unroll
        for (int n = 0; n < 2; ++n) {
            const int c = wid * 32 + n * 16 + (lane & 15);
            const float bv = b_out[c];
            #pragma unroll
            for (int m = 0; m < 2; ++m) {
                const int rb = m * 16 + ((lane >> 4) << 2);
                #pragma unroll
                for (int j = 0; j < 4; ++j) {
                    float x = acc[m][n][j] + bv
                            + features[(size_t)(m0 + rb + j) * 256 + c];
                    v[m][n][j] = x; s[m][j] += x; sq[m][j] += x * x;
                }
            }
        }
        #pragma unroll
        for (int m = 0; m < 2; ++m)
            #pragma unroll
            for (int j = 0; j < 4; ++j) {
                #pragma unroll
                for (int msk = 1; msk <= 8; msk <<= 1) {
                    s[m][j]  += __shfl_xor(s[m][j], msk);
                    sq[m][j] += __shfl_xor(sq[m][j], msk);
                }
                if ((lane & 15) == 0) {
                    const int r = m * 16 + ((lane >> 4) << 2) + j;
                    part[(wid * 32 + r) * 2 + 0] = s[m][j];
                    part[(wid * 32 + r) * 2 + 1] = sq[m][j];
                }
            }
        __syncthreads();
        #pragma unroll
        for (int m = 0; m < 2; ++m) {
            const int rb = m * 16 + ((lane >> 4) << 2);
            #pragma unroll
            for (int j = 0; j < 4; ++j) {
                const int r = rb + j;
                float S = 0.f, SQ = 0.f;
                #pragma unroll
                for (int w = 0; w < 8; ++w) {
                    S += part[(w * 32 + r) * 2 + 0]; SQ += part[(w * 32 + r) * 2 + 1];
                }
                const float mean = S * (1.f / 256.f);
                const float var  = SQ * (1.f / 256.f) - mean * mean;
                const float rstd = rsqrtf(var + LN_EPS);
                #pragma unroll
                for (int n = 0; n < 2; ++n) {
                    const int c = wid * 32 + n * 16 + (lane & 15);
                    const float o = (v[m][n][j] - mean) * rstd * g1[c] + be1[c];
                    xres[m][n][j] = o;
                    const int addr = r * 512 + (((c >> 3) ^ (r & 7)) << 4) + ((c & 7) << 1);
                    *(unsigned short*)(smA + addr) = f2bf(o);
                }
            }
        }
    }
    __syncthreads();

    // ========== P-C: FFN1, rounds 8..15 ==========
    {
        f32x4 acc[2][2];
        #pragma unroll
        for (int m = 0; m < 2; ++m)
            #pragma unroll
            for (int n = 0; n < 2; ++n) acc[m][n] = (f32x4)(0.f);

        #pragma unroll
        for (int i = 8; i < 16; ++i) {
            NSTAGE(i + 2);
            const int kk = (i - 8) & 3, half = (i - 8) >> 2;
            char* Bs = stbuf(i);
            #pragma unroll
            for (int ks = 0; ks < 2; ++ks) {
                bf16x8 af[2], bfr[2];
                #pragma unroll
                for (int m = 0; m < 2; ++m) {
                    const int r = m * 16 + (lane & 15);
                    const int ch = kk * 8 + ks * 4 + (lane >> 4);
                    af[m] = *(const bf16x8*)(smA + r * 512 + ((ch ^ (r & 7)) << 4));
                }
                #pragma unroll
                for (int n = 0; n < 2; ++n) {
                    const int rB = wid * 32 + n * 16 + (lane & 15);
                    bfr[n] = *(const bf16x8*)(Bs + rB * 128
                             + (((ks * 4 + (lane >> 4)) ^ (rB & 7)) << 4));
                }
                #pragma unroll
                for (int m = 0; m < 2; ++m)
                    #pragma unroll
                    for (int n = 0; n < 2; ++n)
                        acc[m][n] = __builtin_amdgcn_mfma_f32_16x16x32_bf16(
                            af[m], bfr[n], acc[m][n], 0, 0, 0);
            }
            bar_vm4();
            if (kk == 3) {
                #pragma unroll
                for (int n = 0; n < 2; ++n) {
                    const int c = half * 256 + wid * 32 + n * 16 + (lane & 15);
                    const float bv = b1[c];
                    #pragma unroll
                    for (int m = 0; m < 2; ++m) {
                        const int rb = m * 16 + ((lane >> 4) << 2);
                        #pragma unroll
                        for (int j = 0; j < 4; ++j) {
                            const int rr = rb + j;
                            const int addr = rr * 1024 + (((c >> 3) ^ (rr & 7)) << 4)
                                           + ((c & 7) << 1);
                            *(unsigned short*)(smH + addr) =
                                f2bf(fmaxf(acc[m][n][j] + bv, 0.f));
                        }
                    }
                }
                #pragma unroll
                for (int m = 0; m < 2; ++m)
                    #pragma unroll
                    for (int n = 0; n < 2; ++n) acc[m][n] = (f32x4)(0.f);
            }
        }
    }
    __syncthreads();

    // ========== P-D: FFN2 K=512, rounds 16..23 + LN2 -> out ==========
    {
        f32x4 acc[2][2];
        #pragma unroll
        for (int m = 0; m < 2; ++m)
            #pragma unroll
            for (int n = 0; n < 2; ++n) acc[m][n] = (f32x4)(0.f);

        #pragma unroll
        for (int i = 16; i < 24; ++i) {
            NSTAGE(i + 2);
            const int k = i - 16;
            char* Bs = stbuf(i);
            #pragma unroll
            for (int ks = 0; ks < 2; ++ks) {
                bf16x8 af[2], bfr[2];
                #pragma unroll
                for (int m = 0; m < 2; ++m) {
                    const int r = m * 16 + (lane & 15);
                    const int ch = k * 8 + ks * 4 + (lane >> 4);
                    af[m] = *(const bf16x8*)(smH + r * 1024 + ((ch ^ (r & 7)) << 4));
                }
                #pragma unroll
                for (int n = 0; n < 2; ++n) {
                    const int rB = wid * 32 + n * 16 + (lane & 15);
                    bfr[n] = *(const bf16x8*)(Bs + rB * 128
                             + (((ks * 4 + (lane >> 4)) ^ (rB & 7)) << 4));
                }
                #pragma unroll
                for (int m = 0; m < 2; ++m)
                    #pragma unroll
                    for (int n = 0; n < 2; ++n)
                        acc[m][n] = __builtin_amdgcn_mfma_f32_16x16x32_bf16(
                            af[m], bfr[n], acc[m][n], 0, 0, 0);
            }
            if (i + 2 < 24) bar_vm4(); else bar_vm0();
        }

        // LN2 epilogue -> out
        float v[2][2][4], s[2][4], sq[2][4];
        #pragma unroll
        for (int m = 0; m < 2; ++m)
            #pragma unroll
            for (int j = 0; j < 4; ++j) { s[m][j] = 0.f; sq[m][j] = 0.f; }
        #pragma unroll
        for (int n = 0; n < 2; ++n) {
            const int c = wid * 32 + n * 16 + (lane & 15);
            const float bv = b2[c];
            #pragma unroll
            for (int m = 0; m < 2; ++m) {
                #pragma unroll
                for (int j = 0; j < 4; ++j) {
                    float x = acc[m][n][j] + bv + xres[m][n][j];
                    v[m][n][j] = x; s[m][j] += x; sq[m][j] += x * x;
                }
            }
        }
        #pragma unroll
        for (int m = 0; m < 2; ++m)
            #pragma unroll
            for (int j = 0; j < 4; ++j) {
                #pragma unroll
                for (int msk = 1; msk <= 8; msk <<= 1) {
                    s[m][j]  += __shfl_xor(s[m][j], msk);
                    sq[m][j] += __shfl_xor(sq[m][j], msk);
                }
                if ((lane & 15) == 0) {
                    const int r = m * 16 + ((lane >> 4) << 2) + j;
                    part[(wid * 32 + r) * 2 + 0] = s[m][j];
                    part[(wid * 32 + r) * 2 + 1] = sq[m][j];
                }
            }
        __syncthreads();
        #pragma unroll
        for (int m = 0; m < 2; ++m) {
            const int rb = m * 16 + ((lane >> 4) << 2);
            #pragma unroll
            for (int j = 0; j < 4; ++j) {
                const int r = rb + j;
                float S = 0.f, SQ = 0.f;
                #pragma unroll
                for (int w = 0; w < 8; ++w) {
                    S += part[(w * 32 + r) * 2 + 0]; SQ += part[(w * 32 + r) * 2 + 1];
                }
                const float mean = S * (1.f / 256.f);
                const float var  = SQ * (1.f / 256.f) - mean * mean;
                const float rstd = rsqrtf(var + LN_EPS);
                #pragma unroll
                for (int n = 0; n < 2; ++n) {
                    const int c = wid * 32 + n * 16 + (lane & 15);
                    out[(size_t)(m0 + r) * 256 + c] =
                        (v[m][n][j] - mean) * rstd * g2[c] + be2[c];
                }
            }
        }
    }
}

// ---------------------------------------------------------------------------
extern "C" void kernel_launch(void* const* d_in, const int* in_sizes, int n_in,
                              void* d_out, int out_size, void* d_ws, size_t ws_size,
                              hipStream_t stream) {
    const float* features = (const float*)d_in[0];
    const float* w_qkv    = (const float*)d_in[1];
    const float* b_qkv    = (const float*)d_in[2];
    const float* w_out    = (const float*)d_in[3];
    const float* b_out    = (const float*)d_in[4];
    const float* w1       = (const float*)d_in[5];
    const float* b1       = (const float*)d_in[6];
    const float* w2       = (const float*)d_in[7];
    const float* b2       = (const float*)d_in[8];
    const float* g1       = (const float*)d_in[9];
    const float* be1      = (const float*)d_in[10];
    const float* g2       = (const float*)d_in[11];
    const float* be2      = (const float*)d_in[12];
    // d_in[13] (mask) structurally determined by WIN=9 -> not read.

    unsigned short* wsu = (unsigned short*)d_ws;
    unsigned short* wconv = wsu;                // wq|wo|w1|w2 bf16: 393,216 els
    unsigned short* kvbf  = wsu + 393216;       // [8192][512]

    // 1) K,V projection (fp32-direct, 2 blocks/CU) + weight conversion
    kv_gemm_f32<<<dim3(128, 4), 512, 0, stream>>>(
        features, w_qkv, b_qkv, w_out, w1, w2, kvbf, wconv);
    // 2) fused tail: Q -> attention -> out-proj+LN1 -> FFN1 -> FFN2+LN2
    tail_fused_pipe2<<<M_ROWS / 32, 512, 0, stream>>>(
        kvbf, wconv, features, b_qkv, b_out, g1, be1, b1, b2, g2, be2,
        (float*)d_out);
}

// Round 17
// 37.472 us; speedup vs baseline: 1.3084x; 1.0227x over previous
//
#include <hip/hip_runtime.h>
#include <math.h>

#define T_LEN 2048
#define LN_EPS 1e-5f
#define M_ROWS 8192

using u16x8  = __attribute__((ext_vector_type(8))) unsigned short;
using bf16x8 = __attribute__((ext_vector_type(8))) short;
using f32x4  = __attribute__((ext_vector_type(4))) float;

__device__ __forceinline__ unsigned short f2bf(float f) {
    unsigned int u = __float_as_uint(f);
    u += 0x7FFFu + ((u >> 16) & 1u);
    return (unsigned short)(u >> 16);
}
__device__ __forceinline__ float bf2f(unsigned short u) {
    return __uint_as_float(((unsigned int)u) << 16);
}
__device__ __forceinline__ u16x8 pack8(float4 a, float4 c) {
    u16x8 p;
    p[0] = f2bf(a.x); p[1] = f2bf(a.y); p[2] = f2bf(a.z); p[3] = f2bf(a.w);
    p[4] = f2bf(c.x); p[5] = f2bf(c.y); p[6] = f2bf(c.z); p[7] = f2bf(c.w);
    return p;
}
__device__ __forceinline__ void gload16(const void* g, void* l) {
    __builtin_amdgcn_global_load_lds(
        (const __attribute__((address_space(1))) unsigned int*)g,
        (__attribute__((address_space(3))) unsigned int*)l, 16, 0, 0);
}
// counted round-barrier: newest 4 loads may stay in flight
__device__ __forceinline__ void bar_vm4() {
    asm volatile("s_waitcnt vmcnt(4)" ::: "memory");
    __builtin_amdgcn_s_barrier();
}
// draining round-barrier (pipeline tail)
__device__ __forceinline__ void bar_vm0() {
    asm volatile("s_waitcnt vmcnt(0)" ::: "memory");
    __builtin_amdgcn_s_barrier();
}

// ---------------------------------------------------------------------------
// K,V GEMM from fp32 inputs: kv[8192,512] = feat @ Wqkv[rows 256..767]^T + b.
// 128x128 tile, 512 threads (8 waves, 2x4), grid 64x4 = 256. Reg-staged
// convert, dbuf. Side job: convert wq|wo|w1|w2 -> bf16 wconv (393216 els).
// ---------------------------------------------------------------------------
__global__ __launch_bounds__(512) void kv_gemm_f32(
    const float* __restrict__ A, const float* __restrict__ Wqkv,
    const float* __restrict__ bias,
    const float* __restrict__ wo, const float* __restrict__ w1,
    const float* __restrict__ w2,
    unsigned short* __restrict__ KV, unsigned short* __restrict__ wconv)
{
    __shared__ char sm[2][32768];        // per buf: As [128][64] | Ws [128][64]

    const int tid = threadIdx.x, lane = tid & 63, wid = tid >> 6;
    const int wr = wid >> 2, wcl = wid & 3;
    const int m0 = blockIdx.x * 128, n0 = blockIdx.y * 128;

    {   // side job: weight conversion (wq from w_qkv rows 0..255)
        const int bid = blockIdx.y * 64 + blockIdx.x;
        const int g = bid * 512 + tid;
        if (g < 49152) {
            const int e = g * 8;
            const float* src; int off;
            if (e < 65536)       { src = Wqkv; off = 0; }        // wq
            else if (e < 131072) { src = wo;   off = 65536; }
            else if (e < 262144) { src = w1;   off = 131072; }
            else                 { src = w2;   off = 262144; }
            const float4 a = *(const float4*)(src + (e - off));
            const float4 c = *(const float4*)(src + (e - off) + 4);
            *(u16x8*)(wconv + e) = pack8(a, c);
        }
    }

    float4 ld[4][2];
    auto LOADR = [&](int k0) {
        #pragma unroll
        for (int j = 0; j < 4; ++j) {
            const int i = j * 512 + tid;
            const float* src;
            if (i < 1024) {
                const int row = i >> 3, k8 = i & 7;
                src = A + (size_t)(m0 + row) * 256 + k0 + k8 * 8;
            } else {
                const int ii = i - 1024;
                const int row = ii >> 3, k8 = ii & 7;
                src = Wqkv + (size_t)(256 + n0 + row) * 256 + k0 + k8 * 8;
            }
            ld[j][0] = *(const float4*)src;
            ld[j][1] = *(const float4*)(src + 4);
        }
    };
    auto CWRITE = [&](char* buf) {
        #pragma unroll
        for (int j = 0; j < 4; ++j) {
            const int i = j * 512 + tid;
            const u16x8 p = pack8(ld[j][0], ld[j][1]);
            if (i < 1024) {
                const int row = i >> 3, k8 = i & 7;
                *(u16x8*)(buf + ((row * 128 + k8 * 16) ^ ((row & 7) << 4))) = p;
            } else {
                const int ii = i - 1024;
                const int row = ii >> 3, k8 = ii & 7;
                *(u16x8*)(buf + 16384 + ((row * 128 + k8 * 16) ^ ((row & 7) << 4))) = p;
            }
        }
    };

    f32x4 acc[4][2];
    #pragma unroll
    for (int m = 0; m < 4; ++m)
        #pragma unroll
        for (int n = 0; n < 2; ++n) acc[m][n] = (f32x4)(0.f);

    LOADR(0);
    CWRITE(sm[0]);
    __syncthreads();

    #pragma unroll
    for (int k = 0; k < 4; ++k) {
        if (k < 3) LOADR((k + 1) * 64);
        char* As = sm[k & 1];
        char* Ws = sm[k & 1] + 16384;
        #pragma unroll
        for (int ks = 0; ks < 2; ++ks) {
            bf16x8 af[4], bfr[2];
            #pragma unroll
            for (int m = 0; m < 4; ++m) {
                const int row = wr * 64 + m * 16 + (lane & 15);
                const int off = (row * 128 + ks * 64 + (lane >> 4) * 16) ^ ((row & 7) << 4);
                af[m] = *(const bf16x8*)(As + off);
            }
            #pragma unroll
            for (int n = 0; n < 2; ++n) {
                const int row = wcl * 32 + n * 16 + (lane & 15);
                const int off = (row * 128 + ks * 64 + (lane >> 4) * 16) ^ ((row & 7) << 4);
                bfr[n] = *(const bf16x8*)(Ws + off);
            }
            #pragma unroll
            for (int m = 0; m < 4; ++m)
                #pragma unroll
                for (int n = 0; n < 2; ++n)
                    acc[m][n] = __builtin_amdgcn_mfma_f32_16x16x32_bf16(
                        af[m], bfr[n], acc[m][n], 0, 0, 0);
        }
        if (k < 3) CWRITE(sm[(k + 1) & 1]);
        __syncthreads();
    }

    #pragma unroll
    for (int n = 0; n < 2; ++n) {
        const int c = n0 + wcl * 32 + n * 16 + (lane & 15);
        const float bv = bias[256 + c];
        #pragma unroll
        for (int m = 0; m < 4; ++m) {
            const int rbase = m0 + wr * 64 + m * 16 + ((lane >> 4) << 2);
            #pragma unroll
            for (int j = 0; j < 4; ++j)
                KV[(size_t)(rbase + j) * 512 + c] = f2bf(acc[m][n][j] + bv);
        }
    }
}

// ---------------------------------------------------------------------------
// Fused tail, 24-round counted-vmcnt pipeline (Wq 0-3 | Wo 4-7 | W1 8-15 |
// W2 16-23): feat->bf16 | Q GEMM | attention | out-proj+res+LN1 | FFN1 |
// FFN2+xres+LN2 -> out. One block = 32 rows, 512 threads.
// LDS: smA 16K | 3x32K stage | smH 32K (aliases smF+smQ early) | part 2K.
// ---------------------------------------------------------------------------
__global__ __launch_bounds__(512) void tail_fused_pipe2(
    const unsigned short* __restrict__ kv, const unsigned short* __restrict__ wconv,
    const float* __restrict__ features, const float* __restrict__ b_qkv,
    const float* __restrict__ b_out,
    const float* __restrict__ g1, const float* __restrict__ be1,
    const float* __restrict__ b1, const float* __restrict__ b2,
    const float* __restrict__ g2, const float* __restrict__ be2,
    float* __restrict__ out)
{
    __shared__ __align__(16) char sm[149504];
    char* smA = sm;                      // [32][512 B]  = 16384
    // stage buffers: sm + 16384 + (i%3)*32768
    char* smH = sm + 114688;             // [32][1024 B] = 32768
    char* smF = smH;                     // alias: [32][512 B] (feat bf16)
    char* smQ = smH + 16384;             // alias: [32][512 B] (Q bf16)
    float* part = (float*)(sm + 147456); // [8][32][2]

    const int tid = threadIdx.x, lane = tid & 63, wid = tid >> 6;
    const int m0 = blockIdx.x * 32;
    const int b = m0 >> 11, t0 = m0 & 2047;

    const unsigned short* Wq = wconv;
    const unsigned short* Wo = wconv + 65536;
    const unsigned short* W1 = wconv + 131072;
    const unsigned short* W2 = wconv + 262144;

    auto stbuf = [&](int i) -> char* { return sm + 16384 + (i % 3) * 32768; };
    auto NSTAGE = [&](int i) {
        if (i >= 24) return;
        const unsigned short* W; int ldk, ro, k0;
        if (i < 4)       { W = Wq; ldk = 256; ro = 0;                    k0 = i * 64; }
        else if (i < 8)  { W = Wo; ldk = 256; ro = 0;                    k0 = (i - 4) * 64; }
        else if (i < 16) { W = W1; ldk = 256; ro = ((i - 8) >> 2) * 256; k0 = ((i - 8) & 3) * 64; }
        else             { W = W2; ldk = 512; ro = 0;                    k0 = (i - 16) * 64; }
        char* dst = stbuf(i);
        #pragma unroll
        for (int j = 0; j < 4; ++j) {
            const int ii = j * 512 + tid, row = ii >> 3, k8 = (ii & 7) ^ (row & 7);
            gload16(W + (size_t)(ro + row) * ldk + k0 + k8 * 8, dst + ii * 16);
        }
    };

    NSTAGE(0); NSTAGE(1);

    // ========== P-F: features rows t0..t0+31 -> smF bf16 (swizzled) ==========
    #pragma unroll
    for (int j = 0; j < 2; ++j) {
        const int i = j * 512 + tid;          // 1024 chunks of 16 B
        const int e = i >> 5, ch = i & 31;
        const float* src = features + ((size_t)(b * T_LEN + t0 + e)) * 256 + ch * 8;
        const float4 a = *(const float4*)src;
        const float4 c = *(const float4*)(src + 4);
        *(u16x8*)(smF + e * 512 + ((ch ^ (e & 7)) << 4)) = pack8(a, c);
    }
    __syncthreads();

    // ========== P-Q: Q GEMM 32x256, rounds 0..3 ==========
    {
        f32x4 acc[2][2];
        #pragma unroll
        for (int m = 0; m < 2; ++m)
            #pragma unroll
            for (int n = 0; n < 2; ++n) acc[m][n] = (f32x4)(0.f);

        #pragma unroll
        for (int i = 0; i < 4; ++i) {
            NSTAGE(i + 2);
            char* Bs = stbuf(i);
            #pragma unroll
            for (int ks = 0; ks < 2; ++ks) {
                bf16x8 af[2], bfr[2];
                #pragma unroll
                for (int m = 0; m < 2; ++m) {
                    const int r = m * 16 + (lane & 15);
                    const int ch = i * 8 + ks * 4 + (lane >> 4);
                    af[m] = *(const bf16x8*)(smF + r * 512 + ((ch ^ (r & 7)) << 4));
                }
                #pragma unroll
                for (int n = 0; n < 2; ++n) {
                    const int rB = wid * 32 + n * 16 + (lane & 15);
                    bfr[n] = *(const bf16x8*)(Bs + rB * 128
                             + (((ks * 4 + (lane >> 4)) ^ (rB & 7)) << 4));
                }
                #pragma unroll
                for (int m = 0; m < 2; ++m)
                    #pragma unroll
                    for (int n = 0; n < 2; ++n)
                        acc[m][n] = __builtin_amdgcn_mfma_f32_16x16x32_bf16(
                            af[m], bfr[n], acc[m][n], 0, 0, 0);
            }
            bar_vm4();
        }
        // Q epilogue: + b_qkv[0..255] -> smQ (bf16, swizzled)
        #pragma unroll
        for (int n = 0; n < 2; ++n) {
            const int c = wid * 32 + n * 16 + (lane & 15);
            const float bv = b_qkv[c];
            #pragma unroll
            for (int m = 0; m < 2; ++m) {
                const int rb = m * 16 + ((lane >> 4) << 2);
                #pragma unroll
                for (int j = 0; j < 4; ++j) {
                    const int r = rb + j;
                    const int addr = r * 512 + (((c >> 3) ^ (r & 7)) << 4) + ((c & 7) << 1);
                    *(unsigned short*)(smQ + addr) = f2bf(acc[m][n][j] + bv);
                }
            }
        }
    }
    __syncthreads();

    // ========== attention: Q from LDS, K/V from kv global ==========
    {
        const int half = tid & 1, p = tid >> 1;
        const int h = p & 7, tl = p >> 3;
        const int t = t0 + tl;
        const unsigned short* kvb = kv + (size_t)b * T_LEN * 512;

        float q[16];
        #pragma unroll
        for (int jj = 0; jj < 2; ++jj) {
            const int ch = h * 4 + half * 2 + jj;
            u16x8 u = *(const u16x8*)(smQ + tl * 512 + ((ch ^ (tl & 7)) << 4));
            #pragma unroll
            for (int e = 0; e < 8; ++e) q[jj * 8 + e] = bf2f(u[e]);
        }
        const unsigned short* kbase = kvb + h * 32 + half * 16;
        const unsigned short* vbase = kvb + 256 + h * 32 + half * 16;

        float sc[9], mx = -1e30f;
        #pragma unroll
        for (int j = 0; j < 9; ++j) {
            const int kr0 = t - 4 + j;
            const int krm = min(max(kr0, 0), T_LEN - 1);
            const unsigned short* kr = kbase + (size_t)krm * 512;
            float d = 0.f;
            #pragma unroll
            for (int jj = 0; jj < 2; ++jj) {
                u16x8 u = *(const u16x8*)(kr + jj * 8);
                #pragma unroll
                for (int e = 0; e < 8; ++e) d += q[jj * 8 + e] * bf2f(u[e]);
            }
            d += __shfl_xor(d, 1);
            sc[j] = (kr0 == krm) ? d * 0.17677669529663687f : -1e30f;
            mx = fmaxf(mx, sc[j]);
        }
        float sum = 0.f;
        #pragma unroll
        for (int j = 0; j < 9; ++j) { sc[j] = expf(sc[j] - mx); sum += sc[j]; }
        const float inv = 1.f / sum;

        float ov[16] = {};
        #pragma unroll
        for (int j = 0; j < 9; ++j) {
            const float pj = sc[j] * inv;
            const int krm = min(max(t - 4 + j, 0), T_LEN - 1);
            const unsigned short* vr = vbase + (size_t)krm * 512;
            #pragma unroll
            for (int jj = 0; jj < 2; ++jj) {
                u16x8 u = *(const u16x8*)(vr + jj * 8);
                #pragma unroll
                for (int e = 0; e < 8; ++e) ov[jj * 8 + e] += pj * bf2f(u[e]);
            }
        }
        #pragma unroll
        for (int jj = 0; jj < 2; ++jj) {
            u16x8 p8;
            #pragma unroll
            for (int e = 0; e < 8; ++e) p8[e] = f2bf(ov[jj * 8 + e]);
            const int ch = h * 4 + half * 2 + jj;
            *(u16x8*)(smA + tl * 512 + ((ch ^ (tl & 7)) << 4)) = p8;
        }
    }
    __syncthreads();

    float xres[2][2][4];

    // ========== P-B: out-proj, rounds 4..7 ==========
    {
        f32x4 acc[2][2];
        #pragma unroll
        for (int m = 0; m < 2; ++m)
            #pragma unroll
            for (int n = 0; n < 2; ++n) acc[m][n] = (f32x4)(0.f);

        #pragma unroll
        for (int i = 4; i < 8; ++i) {
            NSTAGE(i + 2);
            const int kk = i - 4;
            char* Bs = stbuf(i);
            #pragma unroll
            for (int ks = 0; ks < 2; ++ks) {
                bf16x8 af[2], bfr[2];
                #pragma unroll
                for (int m = 0; m < 2; ++m) {
                    const int r = m * 16 + (lane & 15);
                    const int ch = kk * 8 + ks * 4 + (lane >> 4);
                    af[m] = *(const bf16x8*)(smA + r * 512 + ((ch ^ (r & 7)) << 4));
                }
                #pragma unroll
                for (int n = 0; n < 2; ++n) {
                    const int rB = wid * 32 + n * 16 + (lane & 15);
                    bfr[n] = *(const bf16x8*)(Bs + rB * 128
                             + (((ks * 4 + (lane >> 4)) ^ (rB & 7)) << 4));
                }
                #pragma unroll
                for (int m = 0; m < 2; ++m)
                    #pragma unroll
                    for (int n = 0; n < 2; ++n)
                        acc[m][n] = __builtin_amdgcn_mfma_f32_16x16x32_bf16(
                            af[m], bfr[n], acc[m][n], 0, 0, 0);
            }
            bar_vm4();
        }

        // LN1 epilogue
        float v[2][2][4], s[2][4], sq[2][4];
        #pragma unroll
        for (int m = 0; m < 2; ++m)
            #pragma unroll
            for (int j = 0; j < 4; ++j) { s[m][j] = 0.f; sq[m][j] = 0.f; }
        #pragma unroll
        for (int n = 0; n < 2; ++n) {
            const int c = wid * 32 + n * 16 + (lane & 15);
            const float bv = b_out[c];
            #pragma unroll
            for (int m = 0; m < 2; ++m) {
                const int rb = m * 16 + ((lane >> 4) << 2);
                #pragma unroll
                for (int j = 0; j < 4; ++j) {
                    float x = acc[m][n][j] + bv
                            + features[(size_t)(m0 + rb + j) * 256 + c];
                    v[m][n][j] = x; s[m][j] += x; sq[m][j] += x * x;
                }
            }
        }
        #pragma unroll
        for (int m = 0; m < 2; ++m)
            #pragma unroll
            for (int j = 0; j < 4; ++j) {
                #pragma unroll
                for (int msk = 1; msk <= 8; msk <<= 1) {
                    s[m][j]  += __shfl_xor(s[m][j], msk);
                    sq[m][j] += __shfl_xor(sq[m][j], msk);
                }
                if ((lane & 15) == 0) {
                    const int r = m * 16 + ((lane >> 4) << 2) + j;
                    part[(wid * 32 + r) * 2 + 0] = s[m][j];
                    part[(wid * 32 + r) * 2 + 1] = sq[m][j];
                }
            }
        __syncthreads();
        #pragma unroll
        for (int m = 0; m < 2; ++m) {
            const int rb = m * 16 + ((lane >> 4) << 2);
            #pragma unroll
            for (int j = 0; j < 4; ++j) {
                const int r = rb + j;
                float S = 0.f, SQ = 0.f;
                #pragma unroll
                for (int w = 0; w < 8; ++w) {
                    S += part[(w * 32 + r) * 2 + 0]; SQ += part[(w * 32 + r) * 2 + 1];
                }
                const float mean = S * (1.f / 256.f);
                const float var  = SQ * (1.f / 256.f) - mean * mean;
                const float rstd = rsqrtf(var + LN_EPS);
                #pragma unroll
                for (int n = 0; n < 2; ++n) {
                    const int c = wid * 32 + n * 16 + (lane & 15);
                    const float o = (v[m][n][j] - mean) * rstd * g1[c] + be1[c];
                    xres[m][n][j] = o;
                    const int addr = r * 512 + (((c >> 3) ^ (r & 7)) << 4) + ((c & 7) << 1);
                    *(unsigned short*)(smA + addr) = f2bf(o);
                }
            }
        }
    }
    __syncthreads();

    // ========== P-C: FFN1, rounds 8..15 (writes smH; smF/smQ dead) ==========
    {
        f32x4 acc[2][2];
        #pragma unroll
        for (int m = 0; m < 2; ++m)
            #pragma unroll
            for (int n = 0; n < 2; ++n) acc[m][n] = (f32x4)(0.f);

        #pragma unroll
        for (int i = 8; i < 16; ++i) {
            NSTAGE(i + 2);
            const int kk = (i - 8) & 3, half = (i - 8) >> 2;
            char* Bs = stbuf(i);
            #pragma unroll
            for (int ks = 0; ks < 2; ++ks) {
                bf16x8 af[2], bfr[2];
                #pragma unroll
                for (int m = 0; m < 2; ++m) {
                    const int r = m * 16 + (lane & 15);
                    const int ch = kk * 8 + ks * 4 + (lane >> 4);
                    af[m] = *(const bf16x8*)(smA + r * 512 + ((ch ^ (r & 7)) << 4));
                }
                #pragma unroll
                for (int n = 0; n < 2; ++n) {
                    const int rB = wid * 32 + n * 16 + (lane & 15);
                    bfr[n] = *(const bf16x8*)(Bs + rB * 128
                             + (((ks * 4 + (lane >> 4)) ^ (rB & 7)) << 4));
                }
                #pragma unroll
                for (int m = 0; m < 2; ++m)
                    #pragma unroll
                    for (int n = 0; n < 2; ++n)
                        acc[m][n] = __builtin_amdgcn_mfma_f32_16x16x32_bf16(
                            af[m], bfr[n], acc[m][n], 0, 0, 0);
            }
            bar_vm4();
            if (kk == 3) {
                #pragma unroll
                for (int n = 0; n < 2; ++n) {
                    const int c = half * 256 + wid * 32 + n * 16 + (lane & 15);
                    const float bv = b1[c];
                    #pragma unroll
                    for (int m = 0; m < 2; ++m) {
                        const int rb = m * 16 + ((lane >> 4) << 2);
                        #pragma unroll
                        for (int j = 0; j < 4; ++j) {
                            const int rr = rb + j;
                            const int addr = rr * 1024 + (((c >> 3) ^ (rr & 7)) << 4)
                                           + ((c & 7) << 1);
                            *(unsigned short*)(smH + addr) =
                                f2bf(fmaxf(acc[m][n][j] + bv, 0.f));
                        }
                    }
                }
                #pragma unroll
                for (int m = 0; m < 2; ++m)
                    #pragma unroll
                    for (int n = 0; n < 2; ++n) acc[m][n] = (f32x4)(0.f);
            }
        }
    }
    __syncthreads();

    // ========== P-D: FFN2 K=512, rounds 16..23 + LN2 -> out ==========
    {
        f32x4 acc[2][2];
        #pragma unroll
        for (int m = 0; m < 2; ++m)
            #pragma unroll
            for (int n = 0; n < 2; ++n) acc[m][n] = (f32x4)(0.f);

        #pragma unroll
        for (int i = 16; i < 24; ++i) {
            NSTAGE(i + 2);
            const int k = i - 16;
            char* Bs = stbuf(i);
            #pragma unroll
            for (int ks = 0; ks < 2; ++ks) {
                bf16x8 af[2], bfr[2];
                #pragma unroll
                for (int m = 0; m < 2; ++m) {
                    const int r = m * 16 + (lane & 15);
                    const int ch = k * 8 + ks * 4 + (lane >> 4);
                    af[m] = *(const bf16x8*)(smH + r * 1024 + ((ch ^ (r & 7)) << 4));
                }
                #pragma unroll
                for (int n = 0; n < 2; ++n) {
                    const int rB = wid * 32 + n * 16 + (lane & 15);
                    bfr[n] = *(const bf16x8*)(Bs + rB * 128
                             + (((ks * 4 + (lane >> 4)) ^ (rB & 7)) << 4));
                }
                #pragma unroll
                for (int m = 0; m < 2; ++m)
                    #pragma unroll
                    for (int n = 0; n < 2; ++n)
                        acc[m][n] = __builtin_amdgcn_mfma_f32_16x16x32_bf16(
                            af[m], bfr[n], acc[m][n], 0, 0, 0);
            }
            if (i + 2 < 24) bar_vm4(); else bar_vm0();
        }

        // LN2 epilogue -> out
        float v[2][2][4], s[2][4], sq[2][4];
        #pragma unroll
        for (int m = 0; m < 2; ++m)
            #pragma unroll
            for (int j = 0; j < 4; ++j) { s[m][j] = 0.f; sq[m][j] = 0.f; }
        #pragma unroll
        for (int n = 0; n < 2; ++n) {
            const int c = wid * 32 + n * 16 + (lane & 15);
            const float bv = b2[c];
            #pragma unroll
            for (int m = 0; m < 2; ++m) {
                #pragma unroll
                for (int j = 0; j < 4; ++j) {
                    float x = acc[m][n][j] + bv + xres[m][n][j];
                    v[m][n][j] = x; s[m][j] += x; sq[m][j] += x * x;
                }
            }
        }
        #pragma unroll
        for (int m = 0; m < 2; ++m)
            #pragma unroll
            for (int j = 0; j < 4; ++j) {
                #pragma unroll
                for (int msk = 1; msk <= 8; msk <<= 1) {
                    s[m][j]  += __shfl_xor(s[m][j], msk);
                    sq[m][j] += __shfl_xor(sq[m][j], msk);
                }
                if ((lane & 15) == 0) {
                    const int r = m * 16 + ((lane >> 4) << 2) + j;
                    part[(wid * 32 + r) * 2 + 0] = s[m][j];
                    part[(wid * 32 + r) * 2 + 1] = sq[m][j];
                }
            }
        __syncthreads();
        #pragma unroll
        for (int m = 0; m < 2; ++m) {
            const int rb = m * 16 + ((lane >> 4) << 2);
            #pragma unroll
            for (int j = 0; j < 4; ++j) {
                const int r = rb + j;
                float S = 0.f, SQ = 0.f;
                #pragma unroll
                for (int w = 0; w < 8; ++w) {
                    S += part[(w * 32 + r) * 2 + 0]; SQ += part[(w * 32 + r) * 2 + 1];
                }
                const float mean = S * (1.f / 256.f);
                const float var  = SQ * (1.f / 256.f) - mean * mean;
                const float rstd = rsqrtf(var + LN_EPS);
                #pragma unroll
                for (int n = 0; n < 2; ++n) {
                    const int c = wid * 32 + n * 16 + (lane & 15);
                    out[(size_t)(m0 + r) * 256 + c] =
                        (v[m][n][j] - mean) * rstd * g2[c] + be2[c];
                }
            }
        }
    }
}

// ---------------------------------------------------------------------------
extern "C" void kernel_launch(void* const* d_in, const int* in_sizes, int n_in,
                              void* d_out, int out_size, void* d_ws, size_t ws_size,
                              hipStream_t stream) {
    const float* features = (const float*)d_in[0];
    const float* w_qkv    = (const float*)d_in[1];
    const float* b_qkv    = (const float*)d_in[2];
    const float* w_out    = (const float*)d_in[3];
    const float* b_out    = (const float*)d_in[4];
    const float* w1       = (const float*)d_in[5];
    const float* b1       = (const float*)d_in[6];
    const float* w2       = (const float*)d_in[7];
    const float* b2       = (const float*)d_in[8];
    const float* g1       = (const float*)d_in[9];
    const float* be1      = (const float*)d_in[10];
    const float* g2       = (const float*)d_in[11];
    const float* be2      = (const float*)d_in[12];
    // d_in[13] (mask) structurally determined by WIN=9 -> not read.

    unsigned short* wsu = (unsigned short*)d_ws;
    unsigned short* wconv = wsu;                // wq|wo|w1|w2 bf16: 393,216 els
    unsigned short* kvbf  = wsu + 393216;       // [8192][512]

    // 1) K,V projection (fp32-direct) + weight conversion (incl. Wq)
    kv_gemm_f32<<<dim3(64, 4), 512, 0, stream>>>(
        features, w_qkv, b_qkv, w_out, w1, w2, kvbf, wconv);
    // 2) fused tail: Q GEMM -> attention -> out-proj+LN1 -> FFN1 -> FFN2+LN2
    tail_fused_pipe2<<<M_ROWS / 32, 512, 0, stream>>>(
        kvbf, wconv, features, b_qkv, b_out, g1, be1, b1, b2, g2, be2,
        (float*)d_out);
}